// Round 8
// baseline (449.725 us; speedup 1.0000x reference)
//
#include <hip/hip_runtime.h>
#include <stdint.h>

// RGCN round 18: CALIBRATION on the r17 champion (351.0us). The cost model
// is broken (traffic deltas invisible [r17], launch-removal negative [r15],
// bottom-up latency sum ~100-150us vs measured 351) and the fill-masked
// rocprof gives no per-kernel rows. This round duplicates each layer's
// gemm->spmm->bnstat triple (idempotent: deterministic, same inputs, no
// atomics) -> dur delta vs 351.0 == deployed cost of the 3 layer triples
// incl. boundaries. Splits the budget: layers_total = dur-351;
// pack+head+fixed = 351-layers_total. Kernel bodies byte-identical to r17.

typedef float  f32x4  __attribute__((ext_vector_type(4)));
typedef __bf16 bf16x8 __attribute__((ext_vector_type(8)));
typedef __bf16 bf16x4 __attribute__((ext_vector_type(4)));
typedef unsigned short ushort8v __attribute__((ext_vector_type(8)));
typedef uint32_t uint4v __attribute__((ext_vector_type(4)));

#define MBATCH 32
#define ETYPES 4
#define NNODE  512
#define HIDD   128

#define GLB(p) (const __attribute__((address_space(1))) uint32_t*)(p)
#define LDSp(p) (__attribute__((address_space(3))) uint32_t*)(p)

// packed-weight pool offsets (elements)
#define WP_S0 0
#define WP_E0 8192
#define WP_S1 40960
#define WP_E1 57344
#define WP_S2 122880
#define WP_E2 139264
#define WP_W1 204800
#define WP_W2 221184

struct Params {
  const float* x;
  const float* adj;
  const float* wself[3]; const float* bself[3];
  const float* wedge[3]; const float* bedge[3];
  const float* bng[3];   const float* bnb[3];
  const float* w1; const float* b1;
  const float* bnfg; const float* bnfb;
  const float* w2; const float* b2;
  __bf16* mmp; __bf16* hs; __bf16* part;
  __bf16* hb0; __bf16* hb1;
  uint32_t* bm; float* degp; __bf16* wp;
  float* out;
};

// ---------------- phase: pack (r9-proven ballot body) ----------------
__device__ void pack_phase(const float* __restrict__ adj, uint32_t* __restrict__ bm,
                           float* __restrict__ degp, int bid, int t, int nbl) {
  int wave = t >> 6, lane = t & 63;
  for (int rg = bid; rg < 16384; rg += nbl) {
    int r = rg * 4 + wave;                  // 65536 rows (b,e,n)
    int b = r >> 11, e = (r >> 9) & 3, n = r & 511;
    const float* row = adj + (long)r * 512;
    uint32_t myw = 0;
#pragma unroll
    for (int i = 0; i < 8; ++i) {
      uint64_t bal = __ballot(row[i * 64 + lane] != 0.f);
      uint32_t lo = (uint32_t)bal, hi = (uint32_t)(bal >> 32);
      if ((lane >> 1) == i) myw = (lane & 1) ? hi : lo;
    }
    if (lane == (n >> 5)) myw &= ~(1u << (n & 31));   // zero diagonal
    int pc = (lane < 16) ? __popc(myw) : 0;
    pc += __shfl_down(pc, 8);
    pc += __shfl_down(pc, 4);
    pc += __shfl_down(pc, 2);
    pc += __shfl_down(pc, 1);
    if (lane < 16) bm[(long)r * 16 + lane] = myw;
    if (lane == 0) degp[e * 16384 + b * 512 + n] = (float)pc;
  }
}

// ---------------- phase: prep (r9-proven body) ----------------
__device__ void prep_phase(const Params& P, int bid, int t, int nbl) {
  const float* Ws[8] = {P.wself[0], P.wedge[0], P.wself[1], P.wedge[1],
                        P.wself[2], P.wedge[2], P.w1, P.w2};
  const int Kt[8]  = {64, 64, 128, 128, 128, 128, 128, 128};
  const int NB[8]  = {2, 8, 2, 8, 2, 8, 2, 2};
  const int OFF[8] = {WP_S0, WP_E0, WP_S1, WP_E1, WP_S2, WP_E2, WP_W1, WP_W2};
#pragma unroll
  for (int wid = 0; wid < 8; ++wid) {
    int K = Kt[wid], nblk = NB[wid];
    int tot = K * nblk * 64;
    for (int gid = bid * 256 + t; gid < tot; gid += nbl * 256) {
      int c = gid & 63;
      int k = (gid >> 6) % K;
      int blk = (gid >> 6) / K;
      int edge = (nblk == 8);
      int WS = edge ? 512 : 128;
      int col = edge ? (((blk & 1) * 64 + c) * 4 + (blk >> 1)) : (blk * 64 + c);
      P.wp[OFF[wid] + (long)blk * K * 64 + (k >> 3) * 512 + c * 8 + (k & 7)] =
          (__bf16)Ws[wid][k * WS + col];
    }
  }
}

// ---------------- phase: gemm (r17 body) ----------------
template <int K, bool F32IN, bool F32OUT>
__device__ void gemm_phase(char* smem, const void* __restrict__ hv,
                           const __bf16* __restrict__ wp_self,
                           const float* __restrict__ bias_self,
                           const __bf16* __restrict__ wp_edge,
                           const float* __restrict__ bias_edge,
                           const float* __restrict__ degp,
                           float* __restrict__ outF, __bf16* __restrict__ outB,
                           __bf16* __restrict__ mmp,
                           int ntiles, int bid, int t, int nbl) {
  __bf16 (*Hl)[K + 8] = (__bf16(*)[K + 8])smem;
  __bf16* Wl = (__bf16*)(smem + 64 * (K + 8) * 2);   // k-packed [K/8][64][8]
  int wave = t >> 6, lane = t & 63, l15 = lane & 15, q = lane >> 4;
  for (int tile = bid; tile < ntiles; tile += nbl) {
    __syncthreads();                     // smem free from prev tile
    int g0 = (tile & 255) * 64;
    int by = tile >> 8;
    bool edge = by >= 2;
    // stage W: contiguous K*128-byte copy via global_load_lds
    {
      const __bf16* wblk = edge ? (wp_edge + (long)(by - 2) * K * 64)
                                : (wp_self + (long)by * K * 64);
      const char* g = (const char*)wblk;
#pragma unroll
      for (int i = 0; i < K / 32; ++i) {
        __builtin_amdgcn_global_load_lds(GLB(g + i * 4096 + wave * 1024 + lane * 16),
                                         LDSp((char*)Wl + i * 4096 + wave * 1024),
                                         16, 0, 0);
      }
    }
    // stage H (coalesced, padded rows)
    for (int idx = t; idx < 64 * (K / 8); idx += 256) {
      int r = idx / (K / 8), ch = idx % (K / 8);
      if (F32IN) {
        const float* xf = (const float*)hv;
        f32x4 a = *(const f32x4*)(xf + (long)(g0 + r) * K + ch * 8);
        f32x4 bq = *(const f32x4*)(xf + (long)(g0 + r) * K + ch * 8 + 4);
        bf16x8 o;
#pragma unroll
        for (int j = 0; j < 4; ++j) { o[j] = (__bf16)a[j]; o[4 + j] = (__bf16)bq[j]; }
        *(bf16x8*)&Hl[r][ch * 8] = o;
      } else {
        const __bf16* hb = (const __bf16*)hv;
        *(bf16x8*)&Hl[r][ch * 8] = *(const bf16x8*)(hb + (long)(g0 + r) * K + ch * 8);
      }
    }
    __syncthreads();
    f32x4 acc[4] = {};
#pragma unroll
    for (int kk = 0; kk < K / 32; ++kk) {
      bf16x8 af = *(const bf16x8*)&Hl[wave * 16 + l15][kk * 32 + q * 8];
#pragma unroll
      for (int c = 0; c < 4; ++c) {
        bf16x8 bfr = *(const bf16x8*)&Wl[((kk * 4 + q) * 64 + c * 16 + l15) * 8];
        acc[c] = __builtin_amdgcn_mfma_f32_16x16x32_bf16(af, bfr, acc[c], 0, 0, 0);
      }
    }
    // D: row = q*4+i (within wave's 16-row tile), col = c*16+l15
    if (!edge) {
      int c0 = by * 64;
#pragma unroll
      for (int c = 0; c < 4; ++c) {
        float bc = bias_self[c0 + c * 16 + l15];
#pragma unroll
        for (int i = 0; i < 4; ++i) {
          int g = g0 + wave * 16 + q * 4 + i;
          if (F32OUT)
            outF[(long)g * HIDD + c0 + c * 16 + l15] = acc[c][i] + bc;
          else
            outB[(long)g * HIDD + c0 + c * 16 + l15] = (__bf16)(acc[c][i] + bc);
        }
      }
    } else {
      int blk = by - 2;
      int e = blk >> 1, o0 = (blk & 1) * 64;
      float iv[4];
#pragma unroll
      for (int i = 0; i < 4; ++i) {
        int gg = g0 + wave * 16 + q * 4 + i;
        float d = degp[gg] + degp[16384 + gg] + degp[32768 + gg] + degp[49152 + gg];
        iv[i] = d > 0.f ? 1.f / d : 0.f;       // bit-identical to k_inv
      }
      int b4e  = (g0 >> 9) * 4 + e;
      int octg = ((g0 & 511) >> 3) + wave * 2 + (q >> 1);
      int j0   = (q & 1) * 4;
#pragma unroll
      for (int c = 0; c < 4; ++c) {
        int o = o0 + c * 16 + l15;
        float bc = bias_edge[o * 4 + e];
        bf16x4 v4;
#pragma unroll
        for (int i = 0; i < 4; ++i) v4[i] = (__bf16)((acc[c][i] + bc) * iv[i]);
        *(bf16x4*)(mmp + ((long)(b4e * 64 + octg) * HIDD + o) * 8 + j0) = v4;
      }
    }
  }
}

// ---------------- phase: spmm (r13-proven: 4-deep ring pipeline) ----------------
__device__ void spmm_phase(char* smem, const uint32_t* __restrict__ bm,
                           const __bf16* __restrict__ mmp,
                           __bf16* __restrict__ part, int bid, int t) {
  int wave = t >> 6, lane = t & 63, l15 = lane & 15, q = lane >> 4;
  int tile = bid >> 7;                  // 0..7 = nt*2 + oc
  int eb   = bid & 127;                 // e*32 + b
  int e = eb >> 5, b = eb & 31;
  int nt = tile >> 1, oc = tile & 1;
  int n0 = nt * 128, o0 = oc * 64;

  const uint32_t* bmr = bm + ((long)((b * 4 + e) * 512 + n0 + wave * 32 + l15)) * 16;
  uint32_t rm0[16], rm1[16];
#pragma unroll
  for (int i = 0; i < 4; ++i) {
    uint4v v0 = *(const uint4v*)(bmr + i * 4);
    uint4v v1 = *(const uint4v*)(bmr + 256 + i * 4);   // +16 rows * 16 words
    rm0[i * 4 + 0] = v0.x; rm0[i * 4 + 1] = v0.y; rm0[i * 4 + 2] = v0.z; rm0[i * 4 + 3] = v0.w;
    rm1[i * 4 + 0] = v1.x; rm1[i * 4 + 1] = v1.y; rm1[i * 4 + 2] = v1.z; rm1[i * 4 + 3] = v1.w;
  }

  // per-wave stage of phase mc: 2 octets (1 KB each, lane*16 linear dest)
  auto stage = [&](int mc, char* dst) {
#pragma unroll
    for (int i = 0; i < 2; ++i) {
      int oct = wave * 2 + i;
      const char* g = (const char*)mmp +
          ((long)(b * 4 + e) * 65536 + mc * 8192 + oct * 1024 + o0 * 8) * 2;
      __builtin_amdgcn_global_load_lds(GLB(g + lane * 16),
                                       LDSp(dst + oct * 1024), 16, 0, 0);
    }
  };

  stage(0, smem);                      // prologue: 3 phases in flight
  stage(1, smem + 8192);
  stage(2, smem + 16384);

  f32x4 acc0[4] = {}, acc1[4] = {};
#pragma unroll
  for (int mc = 0; mc < 8; ++mc) {
    // wait for phase mc's 2 loads (oldest); leave later phases in flight
    if (mc <= 5)      asm volatile("s_waitcnt vmcnt(4)" ::: "memory");
    else if (mc == 6) asm volatile("s_waitcnt vmcnt(2)" ::: "memory");
    else              asm volatile("s_waitcnt vmcnt(0)" ::: "memory");
    __builtin_amdgcn_s_barrier();
    asm volatile("" ::: "memory");
    if (mc < 5) stage(mc + 3, smem + ((mc + 3) & 3) * 8192);
    const __bf16* Bl = (const __bf16*)(smem + (mc & 3) * 8192);
#pragma unroll
    for (int kk = 0; kk < 2; ++kk) {
      uint32_t bits0 = (rm0[mc * 2 + kk] >> (q * 8)) & 0xffu;
      uint32_t bits1 = (rm1[mc * 2 + kk] >> (q * 8)) & 0xffu;
      ushort8v a0, a1;
#pragma unroll
      for (int j = 0; j < 8; ++j) {
        a0[j] = (bits0 >> j & 1u) ? (unsigned short)0x3F80 : (unsigned short)0;
        a1[j] = (bits1 >> j & 1u) ? (unsigned short)0x3F80 : (unsigned short)0;
      }
      union { ushort8v u; bf16x8 v; } c0, c1; c0.u = a0; c1.u = a1;
#pragma unroll
      for (int c = 0; c < 4; ++c) {
        bf16x8 bfr = *(const bf16x8*)&Bl[((kk * 4 + q) * 64 + c * 16 + l15) * 8];
        acc0[c] = __builtin_amdgcn_mfma_f32_16x16x32_bf16(c0.v, bfr, acc0[c], 0, 0, 0);
        acc1[c] = __builtin_amdgcn_mfma_f32_16x16x32_bf16(c1.v, bfr, acc1[c], 0, 0, 0);
      }
    }
  }

  __bf16* dst = part + (long)(e * 32 + b) * NNODE * HIDD;
#pragma unroll
  for (int c = 0; c < 4; ++c) {
#pragma unroll
    for (int i = 0; i < 4; ++i) {
      int n = n0 + wave * 32 + q * 4 + i;
      int o = o0 + c * 16 + l15;
      dst[(long)n * HIDD + o] = (__bf16)acc0[c][i];
      dst[(long)(n + 16) * HIDD + o] = (__bf16)acc1[c][i];
    }
  }
}

// ---------------- phase: bnstat (r17 body; hs bf16) ----------------
template <bool HASP>
__device__ void bnstat_phase(char* smem, const __bf16* __restrict__ hs,
                             const __bf16* __restrict__ part,
                             const float* __restrict__ gg,
                             const float* __restrict__ bb,
                             __bf16* __restrict__ hb, int bid, int t, int nbl) {
  float* sm = (float*)smem;             // 4096 floats
  float* rs = (float*)(smem + 16384);   // 256
  float* rq = (float*)(smem + 17408);   // 256
  float* bc = (float*)(smem + 18432);   // 2
  int o4 = t & 31, bq = t >> 5;
  for (int n = bid; n < 512; n += nbl) {
    __syncthreads();                    // smem free from previous n
    float s = 0.f, sq = 0.f;
#pragma unroll
    for (int i = 0; i < 4; ++i) {
      int b = bq + i * 8;
      long base = ((long)b * NNODE + n) * HIDD + o4 * 4;
      bf16x4 hv = *(const bf16x4*)(hs + base);
      f32x4 v;
#pragma unroll
      for (int j = 0; j < 4; ++j) v[j] = (float)hv[j];
      if (HASP) {
#pragma unroll
        for (int e = 0; e < 4; ++e) {
          bf16x4 pv = *(const bf16x4*)(part + ((long)(e * 32 + b) * NNODE + n) * HIDD + o4 * 4);
#pragma unroll
          for (int j = 0; j < 4; ++j) v[j] += (float)pv[j];
        }
      }
      *(f32x4*)&sm[b * 128 + o4 * 4] = v;
#pragma unroll
      for (int j = 0; j < 4; ++j) { s += v[j]; sq += v[j] * v[j]; }
    }
    rs[t] = s; rq[t] = sq;
    __syncthreads();
    for (int off = 128; off > 0; off >>= 1) {
      if (t < off) { rs[t] += rs[t + off]; rq[t] += rq[t + off]; }
      __syncthreads();
    }
    if (t == 0) {
      float mean = rs[0] * (1.f / 4096.f);
      float var = rq[0] * (1.f / 4096.f) - mean * mean;   // biased, torch BN1d
      float rstd = rsqrtf(var + 1e-5f);
      float sc = gg[n] * rstd;
      bc[0] = sc;
      bc[1] = bb[n] - mean * sc;
    }
    __syncthreads();
    float sc = bc[0], sh = bc[1];
#pragma unroll
    for (int i = 0; i < 4; ++i) {
      int b = bq + i * 8;
      f32x4 v = *(const f32x4*)&sm[b * 128 + o4 * 4];
      bf16x4 o;
#pragma unroll
      for (int j = 0; j < 4; ++j) {
        float x = v[j] * sc + sh;
        o[j] = (__bf16)(x > 0.f ? x : 0.f);
      }
      *(bf16x4*)(hb + ((long)b * NNODE + n) * HIDD + o4 * 4) = o;
    }
  }
}

// ---------------- kernels ----------------
__global__ __launch_bounds__(256) void g_packprep(Params P) {
  pack_phase(P.adj, P.bm, P.degp, blockIdx.x, threadIdx.x, gridDim.x);
  prep_phase(P, blockIdx.x, threadIdx.x, gridDim.x);
}
template <int K, bool F32IN, bool F32OUT>
__global__ __launch_bounds__(256) void g_gemm(const void* hv, const __bf16* wps,
                                              const float* bs, const __bf16* wpe,
                                              const float* be, const float* degp,
                                              float* outF, __bf16* outB,
                                              __bf16* mmp, int ntiles) {
  __shared__ __align__(16) char smem[64 * (K + 8) * 2 + K * 64 * 2];
  gemm_phase<K, F32IN, F32OUT>(smem, hv, wps, bs, wpe, be, degp, outF, outB,
                               mmp, ntiles, blockIdx.x, threadIdx.x, gridDim.x);
}
__global__ __launch_bounds__(256) void g_spmm(const uint32_t* bm, const __bf16* mmp,
                                              __bf16* part) {
  __shared__ __align__(16) char smem[32768];
  spmm_phase(smem, bm, mmp, part, blockIdx.x, threadIdx.x);
}
template <bool HASP>
__global__ __launch_bounds__(256) void g_bnstat(const __bf16* hs, const __bf16* part,
                                                const float* gg, const float* bb,
                                                __bf16* hb) {
  __shared__ __align__(16) char smem[18448];
  bnstat_phase<HASP>(smem, hs, part, gg, bb, hb, blockIdx.x, threadIdx.x, gridDim.x);
}

extern "C" void kernel_launch(void* const* d_in, const int* in_sizes, int n_in,
                              void* d_out, int out_size, void* d_ws, size_t ws_size,
                              hipStream_t stream) {
  (void)in_sizes; (void)n_in; (void)out_size; (void)ws_size;
  Params P;
  P.x   = (const float*)d_in[0];
  P.adj = (const float*)d_in[1];
  for (int l = 0; l < 3; ++l) {
    P.wself[l] = (const float*)d_in[2 + 6 * l];
    P.bself[l] = (const float*)d_in[3 + 6 * l];
    P.wedge[l] = (const float*)d_in[4 + 6 * l];
    P.bedge[l] = (const float*)d_in[5 + 6 * l];
    P.bng[l]   = (const float*)d_in[6 + 6 * l];
    P.bnb[l]   = (const float*)d_in[7 + 6 * l];
  }
  P.w1   = (const float*)d_in[20];
  P.b1   = (const float*)d_in[21];
  P.bnfg = (const float*)d_in[22];
  P.bnfb = (const float*)d_in[23];
  P.w2   = (const float*)d_in[24];
  P.b2   = (const float*)d_in[25];

  char* ws = (char*)d_ws;
  P.mmp  = (__bf16*)ws;                  // 16,777,216
  P.hs   = (__bf16*)(ws + 16777216);     //  4,194,304 used (slot 8 MB, bf16)
  P.part = (__bf16*)(ws + 25165824);     // 16,777,216 (bf16)
  P.hb0  = (__bf16*)(ws + 41943040);     //  4,194,304
  P.hb1  = (__bf16*)(ws + 46137344);     //  4,194,304
  P.bm   = (uint32_t*)(ws + 50331648);   //  4,194,304
  P.degp = (float*)(ws + 54525952);      //    262,144
  P.wp   = (__bf16*)(ws + 54788096);     //    475,136 -> ~55.3 MB total
  P.out  = (float*)d_out;

  g_packprep<<<16384, 256, 0, stream>>>(P);

  // layer 0 (K=64, fp32 input x) -- triple run TWICE (calibration)
  for (int rep = 0; rep < 2; ++rep) {
    g_gemm<64, true, false><<<2560, 256, 0, stream>>>(P.x, P.wp + WP_S0, P.bself[0],
        P.wp + WP_E0, P.bedge[0], P.degp, nullptr, P.hs, P.mmp, 2560);
    g_spmm<<<1024, 256, 0, stream>>>(P.bm, P.mmp, P.part);
    g_bnstat<true><<<512, 256, 0, stream>>>(P.hs, P.part, P.bng[0], P.bnb[0], P.hb0);
  }

  // layer 1 (K=128) -- triple run TWICE
  for (int rep = 0; rep < 2; ++rep) {
    g_gemm<128, false, false><<<2560, 256, 0, stream>>>(P.hb0, P.wp + WP_S1, P.bself[1],
        P.wp + WP_E1, P.bedge[1], P.degp, nullptr, P.hs, P.mmp, 2560);
    g_spmm<<<1024, 256, 0, stream>>>(P.bm, P.mmp, P.part);
    g_bnstat<true><<<512, 256, 0, stream>>>(P.hs, P.part, P.bng[1], P.bnb[1], P.hb1);
  }

  // layer 2 (K=128) -- triple run TWICE
  for (int rep = 0; rep < 2; ++rep) {
    g_gemm<128, false, false><<<2560, 256, 0, stream>>>(P.hb1, P.wp + WP_S2, P.bself[2],
        P.wp + WP_E2, P.bedge[2], P.degp, nullptr, P.hs, P.mmp, 2560);
    g_spmm<<<1024, 256, 0, stream>>>(P.bm, P.mmp, P.part);
    g_bnstat<true><<<512, 256, 0, stream>>>(P.hs, P.part, P.bng[2], P.bnb[2], P.hb0);
  }

  // head: w1 -> BN -> relu -> w2 (r17 structure)
  g_gemm<128, false, false><<<512, 256, 0, stream>>>(P.hb0, P.wp + WP_W1, P.b1,
      nullptr, nullptr, P.degp, nullptr, P.hs, nullptr, 512);
  g_bnstat<false><<<512, 256, 0, stream>>>(P.hs, nullptr, P.bnfg, P.bnfb, P.hb1);
  g_gemm<128, false, true><<<512, 256, 0, stream>>>(P.hb1, P.wp + WP_W2, P.b2,
      nullptr, nullptr, P.degp, P.out, nullptr, nullptr, 512);
}

// Round 10
// 347.891 us; speedup vs baseline: 1.2927x; 1.2927x over previous
//
#include <hip/hip_runtime.h>
#include <stdint.h>

// RGCN round 19 RESUBMIT (r19 bench died on container acquisition; kernel
// never ran). r18 calibration split the budget: 3 layer triples ~99us warm
// (floor ~42us), pack+head ~20us, ~230us = harness poison-fill + fixed.
// This round applies the r13-proven ring mechanism to the gemm: tile-PAIRING
// (grid 2560->1280; one g0 + by-pair per block). H staged ONCE per pair
// (-21MB/gemm), W double-buffered via global_load_lds with counted vmcnt +
// raw s_barrier -> one HBM exposure per pair instead of two. Pair shares e
// -> iv loaded once. Per-tile math order identical -> absmax 0.03125.
// Everything else (pack, prep, ring-spmm, bnstat, 13-launch chain)
// byte-identical to r17 champion (351.0us).

typedef float  f32x4  __attribute__((ext_vector_type(4)));
typedef __bf16 bf16x8 __attribute__((ext_vector_type(8)));
typedef __bf16 bf16x4 __attribute__((ext_vector_type(4)));
typedef unsigned short ushort8v __attribute__((ext_vector_type(8)));
typedef uint32_t uint4v __attribute__((ext_vector_type(4)));

#define MBATCH 32
#define ETYPES 4
#define NNODE  512
#define HIDD   128

#define GLB(p) (const __attribute__((address_space(1))) uint32_t*)(p)
#define LDSp(p) (__attribute__((address_space(3))) uint32_t*)(p)

// packed-weight pool offsets (elements)
#define WP_S0 0
#define WP_E0 8192
#define WP_S1 40960
#define WP_E1 57344
#define WP_S2 122880
#define WP_E2 139264
#define WP_W1 204800
#define WP_W2 221184

struct Params {
  const float* x;
  const float* adj;
  const float* wself[3]; const float* bself[3];
  const float* wedge[3]; const float* bedge[3];
  const float* bng[3];   const float* bnb[3];
  const float* w1; const float* b1;
  const float* bnfg; const float* bnfb;
  const float* w2; const float* b2;
  __bf16* mmp; __bf16* hs; __bf16* part;
  __bf16* hb0; __bf16* hb1;
  uint32_t* bm; float* degp; __bf16* wp;
  float* out;
};

// ---------------- phase: pack (r9-proven ballot body) ----------------
__device__ void pack_phase(const float* __restrict__ adj, uint32_t* __restrict__ bm,
                           float* __restrict__ degp, int bid, int t, int nbl) {
  int wave = t >> 6, lane = t & 63;
  for (int rg = bid; rg < 16384; rg += nbl) {
    int r = rg * 4 + wave;                  // 65536 rows (b,e,n)
    int b = r >> 11, e = (r >> 9) & 3, n = r & 511;
    const float* row = adj + (long)r * 512;
    uint32_t myw = 0;
#pragma unroll
    for (int i = 0; i < 8; ++i) {
      uint64_t bal = __ballot(row[i * 64 + lane] != 0.f);
      uint32_t lo = (uint32_t)bal, hi = (uint32_t)(bal >> 32);
      if ((lane >> 1) == i) myw = (lane & 1) ? hi : lo;
    }
    if (lane == (n >> 5)) myw &= ~(1u << (n & 31));   // zero diagonal
    int pc = (lane < 16) ? __popc(myw) : 0;
    pc += __shfl_down(pc, 8);
    pc += __shfl_down(pc, 4);
    pc += __shfl_down(pc, 2);
    pc += __shfl_down(pc, 1);
    if (lane < 16) bm[(long)r * 16 + lane] = myw;
    if (lane == 0) degp[e * 16384 + b * 512 + n] = (float)pc;
  }
}

// ---------------- phase: prep (r9-proven body) ----------------
__device__ void prep_phase(const Params& P, int bid, int t, int nbl) {
  const float* Ws[8] = {P.wself[0], P.wedge[0], P.wself[1], P.wedge[1],
                        P.wself[2], P.wedge[2], P.w1, P.w2};
  const int Kt[8]  = {64, 64, 128, 128, 128, 128, 128, 128};
  const int NB[8]  = {2, 8, 2, 8, 2, 8, 2, 2};
  const int OFF[8] = {WP_S0, WP_E0, WP_S1, WP_E1, WP_S2, WP_E2, WP_W1, WP_W2};
#pragma unroll
  for (int wid = 0; wid < 8; ++wid) {
    int K = Kt[wid], nblk = NB[wid];
    int tot = K * nblk * 64;
    for (int gid = bid * 256 + t; gid < tot; gid += nbl * 256) {
      int c = gid & 63;
      int k = (gid >> 6) % K;
      int blk = (gid >> 6) / K;
      int edge = (nblk == 8);
      int WS = edge ? 512 : 128;
      int col = edge ? (((blk & 1) * 64 + c) * 4 + (blk >> 1)) : (blk * 64 + c);
      P.wp[OFF[wid] + (long)blk * K * 64 + (k >> 3) * 512 + c * 8 + (k & 7)] =
          (__bf16)Ws[wid][k * WS + col];
    }
  }
}

// ---------------- phase: gemm (r19: by-pair per block, W dbuf, counted vmcnt) ----
// pair pr covers by1=2pr, by2=2pr+1 for one g0. pr==0: both self (c0 0/64);
// pr>=1: both edge, same e=pr-1, o0 0/64. H staged once per pair.
template <int K, bool F32IN, bool F32OUT>
__device__ void gemm_phase(char* smem, const void* __restrict__ hv,
                           const __bf16* __restrict__ wp_self,
                           const float* __restrict__ bias_self,
                           const __bf16* __restrict__ wp_edge,
                           const float* __restrict__ bias_edge,
                           const float* __restrict__ degp,
                           float* __restrict__ outF, __bf16* __restrict__ outB,
                           __bf16* __restrict__ mmp,
                           int npairs, int bid, int t, int nbl) {
  __bf16 (*Hl)[K + 8] = (__bf16(*)[K + 8])smem;
  __bf16* Wl0 = (__bf16*)(smem + 64 * (K + 8) * 2);   // k-packed [K/8][64][8]
  __bf16* Wl1 = Wl0 + K * 64;
  constexpr int HI = K / 32;           // H chunks per thread
  int wave = t >> 6, lane = t & 63, l15 = lane & 15, q = lane >> 4;
  for (int pairi = bid; pairi < npairs; pairi += nbl) {
    __syncthreads();                   // smem free from prev pair
    int g0 = (pairi & 255) * 64;
    int pr = pairi >> 8;
    // --- H loads first (vmcnt retires in issue order: keeps W countable) ---
    f32x4 ha[F32IN ? HI : 1], hb4[F32IN ? HI : 1];
    bf16x8 hr[F32IN ? 1 : HI];
#pragma unroll
    for (int ii = 0; ii < HI; ++ii) {
      int idx = t + ii * 256;
      int r = idx / (K / 8), ch = idx % (K / 8);
      if (F32IN) {
        const float* xf = (const float*)hv;
        ha[ii]  = *(const f32x4*)(xf + (long)(g0 + r) * K + ch * 8);
        hb4[ii] = *(const f32x4*)(xf + (long)(g0 + r) * K + ch * 8 + 4);
      } else {
        const __bf16* hbp = (const __bf16*)hv;
        hr[ii] = *(const bf16x8*)(hbp + (long)(g0 + r) * K + ch * 8);
      }
    }
    __builtin_amdgcn_sched_barrier(0);
    // --- issue W1 then W2 (K/32 gload_lds each per wave) ---
    {
      const __bf16* wb1 = (pr >= 1) ? (wp_edge + (long)(pr * 2 - 2) * K * 64)
                                    : wp_self;
      const __bf16* wb2 = (pr >= 1) ? (wp_edge + (long)(pr * 2 - 1) * K * 64)
                                    : (wp_self + (long)K * 64);
      const char* g1 = (const char*)wb1;
      const char* g2 = (const char*)wb2;
#pragma unroll
      for (int i = 0; i < K / 32; ++i)
        __builtin_amdgcn_global_load_lds(GLB(g1 + i * 4096 + wave * 1024 + lane * 16),
                                         LDSp((char*)Wl0 + i * 4096 + wave * 1024),
                                         16, 0, 0);
#pragma unroll
      for (int i = 0; i < K / 32; ++i)
        __builtin_amdgcn_global_load_lds(GLB(g2 + i * 4096 + wave * 1024 + lane * 16),
                                         LDSp((char*)Wl1 + i * 4096 + wave * 1024),
                                         16, 0, 0);
    }
    __builtin_amdgcn_sched_barrier(0);
    // --- H -> LDS (compiler waits H loads at vmcnt>=2*K/32: W stays in flight) ---
#pragma unroll
    for (int ii = 0; ii < HI; ++ii) {
      int idx = t + ii * 256;
      int r = idx / (K / 8), ch = idx % (K / 8);
      if (F32IN) {
        bf16x8 o;
#pragma unroll
        for (int j = 0; j < 4; ++j) { o[j] = (__bf16)ha[ii][j]; o[4 + j] = (__bf16)hb4[ii][j]; }
        *(bf16x8*)&Hl[r][ch * 8] = o;
      } else {
        *(bf16x8*)&Hl[r][ch * 8] = hr[ii];
      }
    }
    asm volatile("s_waitcnt lgkmcnt(0)" ::: "memory");   // H in LDS
    if (K == 128) asm volatile("s_waitcnt vmcnt(4)" ::: "memory");  // W1 done
    else          asm volatile("s_waitcnt vmcnt(2)" ::: "memory");
    __builtin_amdgcn_s_barrier();
    asm volatile("" ::: "memory");
    // --- MFMA tile 1 (Wl0) ---
    f32x4 acc1[4] = {}, acc2[4] = {};
#pragma unroll
    for (int kk = 0; kk < K / 32; ++kk) {
      bf16x8 af = *(const bf16x8*)&Hl[wave * 16 + l15][kk * 32 + q * 8];
#pragma unroll
      for (int c = 0; c < 4; ++c) {
        bf16x8 bfr = *(const bf16x8*)&Wl0[((kk * 4 + q) * 64 + c * 16 + l15) * 8];
        acc1[c] = __builtin_amdgcn_mfma_f32_16x16x32_bf16(af, bfr, acc1[c], 0, 0, 0);
      }
    }
    asm volatile("s_waitcnt vmcnt(0)" ::: "memory");     // W2 done (no stores yet)
    __builtin_amdgcn_s_barrier();
    asm volatile("" ::: "memory");
    // --- MFMA tile 2 (Wl1) ---
#pragma unroll
    for (int kk = 0; kk < K / 32; ++kk) {
      bf16x8 af = *(const bf16x8*)&Hl[wave * 16 + l15][kk * 32 + q * 8];
#pragma unroll
      for (int c = 0; c < 4; ++c) {
        bf16x8 bfr = *(const bf16x8*)&Wl1[((kk * 4 + q) * 64 + c * 16 + l15) * 8];
        acc2[c] = __builtin_amdgcn_mfma_f32_16x16x32_bf16(af, bfr, acc2[c], 0, 0, 0);
      }
    }
    // --- epilogues ---
    if (pr == 0) {                      // two self tiles: c0 = 0 and 64
#pragma unroll
      for (int h = 0; h < 2; ++h) {
        f32x4* acc = h ? acc2 : acc1;
        int c0 = h * 64;
#pragma unroll
        for (int c = 0; c < 4; ++c) {
          float bc = bias_self[c0 + c * 16 + l15];
#pragma unroll
          for (int i = 0; i < 4; ++i) {
            int g = g0 + wave * 16 + q * 4 + i;
            if (F32OUT)
              outF[(long)g * HIDD + c0 + c * 16 + l15] = acc[c][i] + bc;
            else
              outB[(long)g * HIDD + c0 + c * 16 + l15] = (__bf16)(acc[c][i] + bc);
          }
        }
      }
    } else {                            // two edge tiles: same e, o0 = 0 and 64
      int e = pr - 1;
      float iv[4];
#pragma unroll
      for (int i = 0; i < 4; ++i) {
        int gg = g0 + wave * 16 + q * 4 + i;
        float d = degp[gg] + degp[16384 + gg] + degp[32768 + gg] + degp[49152 + gg];
        iv[i] = d > 0.f ? 1.f / d : 0.f;       // bit-identical to k_inv
      }
      int b4e  = (g0 >> 9) * 4 + e;
      int octg = ((g0 & 511) >> 3) + wave * 2 + (q >> 1);
      int j0   = (q & 1) * 4;
#pragma unroll
      for (int h = 0; h < 2; ++h) {
        f32x4* acc = h ? acc2 : acc1;
        int o0 = h * 64;
#pragma unroll
        for (int c = 0; c < 4; ++c) {
          int o = o0 + c * 16 + l15;
          float bc = bias_edge[o * 4 + e];
          bf16x4 v4;
#pragma unroll
          for (int i = 0; i < 4; ++i) v4[i] = (__bf16)((acc[c][i] + bc) * iv[i]);
          *(bf16x4*)(mmp + ((long)(b4e * 64 + octg) * HIDD + o) * 8 + j0) = v4;
        }
      }
    }
  }
}

// ---------------- phase: spmm (r13-proven: 4-deep ring pipeline) ----------------
__device__ void spmm_phase(char* smem, const uint32_t* __restrict__ bm,
                           const __bf16* __restrict__ mmp,
                           __bf16* __restrict__ part, int bid, int t) {
  int wave = t >> 6, lane = t & 63, l15 = lane & 15, q = lane >> 4;
  int tile = bid >> 7;                  // 0..7 = nt*2 + oc
  int eb   = bid & 127;                 // e*32 + b
  int e = eb >> 5, b = eb & 31;
  int nt = tile >> 1, oc = tile & 1;
  int n0 = nt * 128, o0 = oc * 64;

  const uint32_t* bmr = bm + ((long)((b * 4 + e) * 512 + n0 + wave * 32 + l15)) * 16;
  uint32_t rm0[16], rm1[16];
#pragma unroll
  for (int i = 0; i < 4; ++i) {
    uint4v v0 = *(const uint4v*)(bmr + i * 4);
    uint4v v1 = *(const uint4v*)(bmr + 256 + i * 4);   // +16 rows * 16 words
    rm0[i * 4 + 0] = v0.x; rm0[i * 4 + 1] = v0.y; rm0[i * 4 + 2] = v0.z; rm0[i * 4 + 3] = v0.w;
    rm1[i * 4 + 0] = v1.x; rm1[i * 4 + 1] = v1.y; rm1[i * 4 + 2] = v1.z; rm1[i * 4 + 3] = v1.w;
  }

  // per-wave stage of phase mc: 2 octets (1 KB each, lane*16 linear dest)
  auto stage = [&](int mc, char* dst) {
#pragma unroll
    for (int i = 0; i < 2; ++i) {
      int oct = wave * 2 + i;
      const char* g = (const char*)mmp +
          ((long)(b * 4 + e) * 65536 + mc * 8192 + oct * 1024 + o0 * 8) * 2;
      __builtin_amdgcn_global_load_lds(GLB(g + lane * 16),
                                       LDSp(dst + oct * 1024), 16, 0, 0);
    }
  };

  stage(0, smem);                      // prologue: 3 phases in flight
  stage(1, smem + 8192);
  stage(2, smem + 16384);

  f32x4 acc0[4] = {}, acc1[4] = {};
#pragma unroll
  for (int mc = 0; mc < 8; ++mc) {
    // wait for phase mc's 2 loads (oldest); leave later phases in flight
    if (mc <= 5)      asm volatile("s_waitcnt vmcnt(4)" ::: "memory");
    else if (mc == 6) asm volatile("s_waitcnt vmcnt(2)" ::: "memory");
    else              asm volatile("s_waitcnt vmcnt(0)" ::: "memory");
    __builtin_amdgcn_s_barrier();
    asm volatile("" ::: "memory");
    if (mc < 5) stage(mc + 3, smem + ((mc + 3) & 3) * 8192);
    const __bf16* Bl = (const __bf16*)(smem + (mc & 3) * 8192);
#pragma unroll
    for (int kk = 0; kk < 2; ++kk) {
      uint32_t bits0 = (rm0[mc * 2 + kk] >> (q * 8)) & 0xffu;
      uint32_t bits1 = (rm1[mc * 2 + kk] >> (q * 8)) & 0xffu;
      ushort8v a0, a1;
#pragma unroll
      for (int j = 0; j < 8; ++j) {
        a0[j] = (bits0 >> j & 1u) ? (unsigned short)0x3F80 : (unsigned short)0;
        a1[j] = (bits1 >> j & 1u) ? (unsigned short)0x3F80 : (unsigned short)0;
      }
      union { ushort8v u; bf16x8 v; } c0, c1; c0.u = a0; c1.u = a1;
#pragma unroll
      for (int c = 0; c < 4; ++c) {
        bf16x8 bfr = *(const bf16x8*)&Bl[((kk * 4 + q) * 64 + c * 16 + l15) * 8];
        acc0[c] = __builtin_amdgcn_mfma_f32_16x16x32_bf16(c0.v, bfr, acc0[c], 0, 0, 0);
        acc1[c] = __builtin_amdgcn_mfma_f32_16x16x32_bf16(c1.v, bfr, acc1[c], 0, 0, 0);
      }
    }
  }

  __bf16* dst = part + (long)(e * 32 + b) * NNODE * HIDD;
#pragma unroll
  for (int c = 0; c < 4; ++c) {
#pragma unroll
    for (int i = 0; i < 4; ++i) {
      int n = n0 + wave * 32 + q * 4 + i;
      int o = o0 + c * 16 + l15;
      dst[(long)n * HIDD + o] = (__bf16)acc0[c][i];
      dst[(long)(n + 16) * HIDD + o] = (__bf16)acc1[c][i];
    }
  }
}

// ---------------- phase: bnstat (r17 body; hs bf16) ----------------
template <bool HASP>
__device__ void bnstat_phase(char* smem, const __bf16* __restrict__ hs,
                             const __bf16* __restrict__ part,
                             const float* __restrict__ gg,
                             const float* __restrict__ bb,
                             __bf16* __restrict__ hb, int bid, int t, int nbl) {
  float* sm = (float*)smem;             // 4096 floats
  float* rs = (float*)(smem + 16384);   // 256
  float* rq = (float*)(smem + 17408);   // 256
  float* bc = (float*)(smem + 18432);   // 2
  int o4 = t & 31, bq = t >> 5;
  for (int n = bid; n < 512; n += nbl) {
    __syncthreads();                    // smem free from previous n
    float s = 0.f, sq = 0.f;
#pragma unroll
    for (int i = 0; i < 4; ++i) {
      int b = bq + i * 8;
      long base = ((long)b * NNODE + n) * HIDD + o4 * 4;
      bf16x4 hv = *(const bf16x4*)(hs + base);
      f32x4 v;
#pragma unroll
      for (int j = 0; j < 4; ++j) v[j] = (float)hv[j];
      if (HASP) {
#pragma unroll
        for (int e = 0; e < 4; ++e) {
          bf16x4 pv = *(const bf16x4*)(part + ((long)(e * 32 + b) * NNODE + n) * HIDD + o4 * 4);
#pragma unroll
          for (int j = 0; j < 4; ++j) v[j] += (float)pv[j];
        }
      }
      *(f32x4*)&sm[b * 128 + o4 * 4] = v;
#pragma unroll
      for (int j = 0; j < 4; ++j) { s += v[j]; sq += v[j] * v[j]; }
    }
    rs[t] = s; rq[t] = sq;
    __syncthreads();
    for (int off = 128; off > 0; off >>= 1) {
      if (t < off) { rs[t] += rs[t + off]; rq[t] += rq[t + off]; }
      __syncthreads();
    }
    if (t == 0) {
      float mean = rs[0] * (1.f / 4096.f);
      float var = rq[0] * (1.f / 4096.f) - mean * mean;   // biased, torch BN1d
      float rstd = rsqrtf(var + 1e-5f);
      float sc = gg[n] * rstd;
      bc[0] = sc;
      bc[1] = bb[n] - mean * sc;
    }
    __syncthreads();
    float sc = bc[0], sh = bc[1];
#pragma unroll
    for (int i = 0; i < 4; ++i) {
      int b = bq + i * 8;
      f32x4 v = *(const f32x4*)&sm[b * 128 + o4 * 4];
      bf16x4 o;
#pragma unroll
      for (int j = 0; j < 4; ++j) {
        float x = v[j] * sc + sh;
        o[j] = (__bf16)(x > 0.f ? x : 0.f);
      }
      *(bf16x4*)(hb + ((long)b * NNODE + n) * HIDD + o4 * 4) = o;
    }
  }
}

// ---------------- kernels ----------------
__global__ __launch_bounds__(256) void g_packprep(Params P) {
  pack_phase(P.adj, P.bm, P.degp, blockIdx.x, threadIdx.x, gridDim.x);
  prep_phase(P, blockIdx.x, threadIdx.x, gridDim.x);
}
template <int K, bool F32IN, bool F32OUT>
__global__ __launch_bounds__(256) void g_gemm(const void* hv, const __bf16* wps,
                                              const float* bs, const __bf16* wpe,
                                              const float* be, const float* degp,
                                              float* outF, __bf16* outB,
                                              __bf16* mmp, int npairs) {
  __shared__ __align__(16) char smem[64 * (K + 8) * 2 + 2 * K * 64 * 2];
  gemm_phase<K, F32IN, F32OUT>(smem, hv, wps, bs, wpe, be, degp, outF, outB,
                               mmp, npairs, blockIdx.x, threadIdx.x, gridDim.x);
}
__global__ __launch_bounds__(256) void g_spmm(const uint32_t* bm, const __bf16* mmp,
                                              __bf16* part) {
  __shared__ __align__(16) char smem[32768];
  spmm_phase(smem, bm, mmp, part, blockIdx.x, threadIdx.x);
}
template <bool HASP>
__global__ __launch_bounds__(256) void g_bnstat(const __bf16* hs, const __bf16* part,
                                                const float* gg, const float* bb,
                                                __bf16* hb) {
  __shared__ __align__(16) char smem[18448];
  bnstat_phase<HASP>(smem, hs, part, gg, bb, hb, blockIdx.x, threadIdx.x, gridDim.x);
}

extern "C" void kernel_launch(void* const* d_in, const int* in_sizes, int n_in,
                              void* d_out, int out_size, void* d_ws, size_t ws_size,
                              hipStream_t stream) {
  (void)in_sizes; (void)n_in; (void)out_size; (void)ws_size;
  Params P;
  P.x   = (const float*)d_in[0];
  P.adj = (const float*)d_in[1];
  for (int l = 0; l < 3; ++l) {
    P.wself[l] = (const float*)d_in[2 + 6 * l];
    P.bself[l] = (const float*)d_in[3 + 6 * l];
    P.wedge[l] = (const float*)d_in[4 + 6 * l];
    P.bedge[l] = (const float*)d_in[5 + 6 * l];
    P.bng[l]   = (const float*)d_in[6 + 6 * l];
    P.bnb[l]   = (const float*)d_in[7 + 6 * l];
  }
  P.w1   = (const float*)d_in[20];
  P.b1   = (const float*)d_in[21];
  P.bnfg = (const float*)d_in[22];
  P.bnfb = (const float*)d_in[23];
  P.w2   = (const float*)d_in[24];
  P.b2   = (const float*)d_in[25];

  char* ws = (char*)d_ws;
  P.mmp  = (__bf16*)ws;                  // 16,777,216
  P.hs   = (__bf16*)(ws + 16777216);     //  4,194,304 used (slot 8 MB, bf16)
  P.part = (__bf16*)(ws + 25165824);     // 16,777,216 (bf16)
  P.hb0  = (__bf16*)(ws + 41943040);     //  4,194,304
  P.hb1  = (__bf16*)(ws + 46137344);     //  4,194,304
  P.bm   = (uint32_t*)(ws + 50331648);   //  4,194,304
  P.degp = (float*)(ws + 54525952);      //    262,144
  P.wp   = (__bf16*)(ws + 54788096);     //    475,136 -> ~55.3 MB total
  P.out  = (float*)d_out;

  g_packprep<<<16384, 256, 0, stream>>>(P);

  // layer 0 (K=64, fp32 input x): 1280 by-pairs
  g_gemm<64, true, false><<<1280, 256, 0, stream>>>(P.x, P.wp + WP_S0, P.bself[0],
      P.wp + WP_E0, P.bedge[0], P.degp, nullptr, P.hs, P.mmp, 1280);
  g_spmm<<<1024, 256, 0, stream>>>(P.bm, P.mmp, P.part);
  g_bnstat<true><<<512, 256, 0, stream>>>(P.hs, P.part, P.bng[0], P.bnb[0], P.hb0);

  // layer 1 (K=128)
  g_gemm<128, false, false><<<1280, 256, 0, stream>>>(P.hb0, P.wp + WP_S1, P.bself[1],
      P.wp + WP_E1, P.bedge[1], P.degp, nullptr, P.hs, P.mmp, 1280);
  g_spmm<<<1024, 256, 0, stream>>>(P.bm, P.mmp, P.part);
  g_bnstat<true><<<512, 256, 0, stream>>>(P.hs, P.part, P.bng[1], P.bnb[1], P.hb1);

  // layer 2 (K=128)
  g_gemm<128, false, false><<<1280, 256, 0, stream>>>(P.hb1, P.wp + WP_S2, P.bself[2],
      P.wp + WP_E2, P.bedge[2], P.degp, nullptr, P.hs, P.mmp, 1280);
  g_spmm<<<1024, 256, 0, stream>>>(P.bm, P.mmp, P.part);
  g_bnstat<true><<<512, 256, 0, stream>>>(P.hs, P.part, P.bng[2], P.bnb[2], P.hb0);

  // head: w1 -> BN -> relu -> w2 (pairs: 256 each, self-only)
  g_gemm<128, false, false><<<256, 256, 0, stream>>>(P.hb0, P.wp + WP_W1, P.b1,
      nullptr, nullptr, P.degp, nullptr, P.hs, nullptr, 256);
  g_bnstat<false><<<512, 256, 0, stream>>>(P.hs, nullptr, P.bnfg, P.bnfb, P.hb1);
  g_gemm<128, false, true><<<256, 256, 0, stream>>>(P.hb1, P.wp + WP_W2, P.b2,
      nullptr, nullptr, P.degp, P.out, nullptr, nullptr, 256);
}

// Round 11
// 346.497 us; speedup vs baseline: 1.2979x; 1.0040x over previous
//
#include <hip/hip_runtime.h>
#include <stdint.h>

// RGCN round 20. Base = r19 champion (347.9us: ring-spmm + paired gemm).
// Insight from r17/r19: all intermediates are L3-resident (55MB workspace
// vs 256MB L3) -> traffic cuts are worthless; only exposure-count and
// serialization cuts pay. ONE change: bnstat rewritten barrier-free.
// Old: 256 threads/n, LDS staging + 8-step tree reduce = ~11 syncthreads
// per n, 2 blocks/CU. New: ONE WAVE per n (512 blocks x 64 threads), 16
// bf16x4 chunks per lane held in REGISTERS, shfl_xor tree reduce (6 steps),
// sc/sh computed per-lane, normalize from registers -> zero barriers, zero
// LDS. 80 independent loads/lane covers L3 latency. Sum grouping changes
// (wave tree vs block tree) -> BN stats perturb ~1e-7 rel; absmax stays
// 0.03125 (dominated by bf16 output rounding). All else byte-identical.

typedef float  f32x4  __attribute__((ext_vector_type(4)));
typedef __bf16 bf16x8 __attribute__((ext_vector_type(8)));
typedef __bf16 bf16x4 __attribute__((ext_vector_type(4)));
typedef unsigned short ushort8v __attribute__((ext_vector_type(8)));
typedef uint32_t uint4v __attribute__((ext_vector_type(4)));

#define MBATCH 32
#define ETYPES 4
#define NNODE  512
#define HIDD   128

#define GLB(p) (const __attribute__((address_space(1))) uint32_t*)(p)
#define LDSp(p) (__attribute__((address_space(3))) uint32_t*)(p)

// packed-weight pool offsets (elements)
#define WP_S0 0
#define WP_E0 8192
#define WP_S1 40960
#define WP_E1 57344
#define WP_S2 122880
#define WP_E2 139264
#define WP_W1 204800
#define WP_W2 221184

struct Params {
  const float* x;
  const float* adj;
  const float* wself[3]; const float* bself[3];
  const float* wedge[3]; const float* bedge[3];
  const float* bng[3];   const float* bnb[3];
  const float* w1; const float* b1;
  const float* bnfg; const float* bnfb;
  const float* w2; const float* b2;
  __bf16* mmp; __bf16* hs; __bf16* part;
  __bf16* hb0; __bf16* hb1;
  uint32_t* bm; float* degp; __bf16* wp;
  float* out;
};

// ---------------- phase: pack (r9-proven ballot body) ----------------
__device__ void pack_phase(const float* __restrict__ adj, uint32_t* __restrict__ bm,
                           float* __restrict__ degp, int bid, int t, int nbl) {
  int wave = t >> 6, lane = t & 63;
  for (int rg = bid; rg < 16384; rg += nbl) {
    int r = rg * 4 + wave;                  // 65536 rows (b,e,n)
    int b = r >> 11, e = (r >> 9) & 3, n = r & 511;
    const float* row = adj + (long)r * 512;
    uint32_t myw = 0;
#pragma unroll
    for (int i = 0; i < 8; ++i) {
      uint64_t bal = __ballot(row[i * 64 + lane] != 0.f);
      uint32_t lo = (uint32_t)bal, hi = (uint32_t)(bal >> 32);
      if ((lane >> 1) == i) myw = (lane & 1) ? hi : lo;
    }
    if (lane == (n >> 5)) myw &= ~(1u << (n & 31));   // zero diagonal
    int pc = (lane < 16) ? __popc(myw) : 0;
    pc += __shfl_down(pc, 8);
    pc += __shfl_down(pc, 4);
    pc += __shfl_down(pc, 2);
    pc += __shfl_down(pc, 1);
    if (lane < 16) bm[(long)r * 16 + lane] = myw;
    if (lane == 0) degp[e * 16384 + b * 512 + n] = (float)pc;
  }
}

// ---------------- phase: prep (r9-proven body) ----------------
__device__ void prep_phase(const Params& P, int bid, int t, int nbl) {
  const float* Ws[8] = {P.wself[0], P.wedge[0], P.wself[1], P.wedge[1],
                        P.wself[2], P.wedge[2], P.w1, P.w2};
  const int Kt[8]  = {64, 64, 128, 128, 128, 128, 128, 128};
  const int NB[8]  = {2, 8, 2, 8, 2, 8, 2, 2};
  const int OFF[8] = {WP_S0, WP_E0, WP_S1, WP_E1, WP_S2, WP_E2, WP_W1, WP_W2};
#pragma unroll
  for (int wid = 0; wid < 8; ++wid) {
    int K = Kt[wid], nblk = NB[wid];
    int tot = K * nblk * 64;
    for (int gid = bid * 256 + t; gid < tot; gid += nbl * 256) {
      int c = gid & 63;
      int k = (gid >> 6) % K;
      int blk = (gid >> 6) / K;
      int edge = (nblk == 8);
      int WS = edge ? 512 : 128;
      int col = edge ? (((blk & 1) * 64 + c) * 4 + (blk >> 1)) : (blk * 64 + c);
      P.wp[OFF[wid] + (long)blk * K * 64 + (k >> 3) * 512 + c * 8 + (k & 7)] =
          (__bf16)Ws[wid][k * WS + col];
    }
  }
}

// ---------------- phase: gemm (r19: by-pair per block, W dbuf, counted vmcnt) ----
// pair pr covers by1=2pr, by2=2pr+1 for one g0. pr==0: both self (c0 0/64);
// pr>=1: both edge, same e=pr-1, o0 0/64. H staged once per pair.
template <int K, bool F32IN, bool F32OUT>
__device__ void gemm_phase(char* smem, const void* __restrict__ hv,
                           const __bf16* __restrict__ wp_self,
                           const float* __restrict__ bias_self,
                           const __bf16* __restrict__ wp_edge,
                           const float* __restrict__ bias_edge,
                           const float* __restrict__ degp,
                           float* __restrict__ outF, __bf16* __restrict__ outB,
                           __bf16* __restrict__ mmp,
                           int npairs, int bid, int t, int nbl) {
  __bf16 (*Hl)[K + 8] = (__bf16(*)[K + 8])smem;
  __bf16* Wl0 = (__bf16*)(smem + 64 * (K + 8) * 2);   // k-packed [K/8][64][8]
  __bf16* Wl1 = Wl0 + K * 64;
  constexpr int HI = K / 32;           // H chunks per thread
  int wave = t >> 6, lane = t & 63, l15 = lane & 15, q = lane >> 4;
  for (int pairi = bid; pairi < npairs; pairi += nbl) {
    __syncthreads();                   // smem free from prev pair
    int g0 = (pairi & 255) * 64;
    int pr = pairi >> 8;
    // --- H loads first (vmcnt retires in issue order: keeps W countable) ---
    f32x4 ha[F32IN ? HI : 1], hb4[F32IN ? HI : 1];
    bf16x8 hr[F32IN ? 1 : HI];
#pragma unroll
    for (int ii = 0; ii < HI; ++ii) {
      int idx = t + ii * 256;
      int r = idx / (K / 8), ch = idx % (K / 8);
      if (F32IN) {
        const float* xf = (const float*)hv;
        ha[ii]  = *(const f32x4*)(xf + (long)(g0 + r) * K + ch * 8);
        hb4[ii] = *(const f32x4*)(xf + (long)(g0 + r) * K + ch * 8 + 4);
      } else {
        const __bf16* hbp = (const __bf16*)hv;
        hr[ii] = *(const bf16x8*)(hbp + (long)(g0 + r) * K + ch * 8);
      }
    }
    __builtin_amdgcn_sched_barrier(0);
    // --- issue W1 then W2 (K/32 gload_lds each per wave) ---
    {
      const __bf16* wb1 = (pr >= 1) ? (wp_edge + (long)(pr * 2 - 2) * K * 64)
                                    : wp_self;
      const __bf16* wb2 = (pr >= 1) ? (wp_edge + (long)(pr * 2 - 1) * K * 64)
                                    : (wp_self + (long)K * 64);
      const char* g1 = (const char*)wb1;
      const char* g2 = (const char*)wb2;
#pragma unroll
      for (int i = 0; i < K / 32; ++i)
        __builtin_amdgcn_global_load_lds(GLB(g1 + i * 4096 + wave * 1024 + lane * 16),
                                         LDSp((char*)Wl0 + i * 4096 + wave * 1024),
                                         16, 0, 0);
#pragma unroll
      for (int i = 0; i < K / 32; ++i)
        __builtin_amdgcn_global_load_lds(GLB(g2 + i * 4096 + wave * 1024 + lane * 16),
                                         LDSp((char*)Wl1 + i * 4096 + wave * 1024),
                                         16, 0, 0);
    }
    __builtin_amdgcn_sched_barrier(0);
    // --- H -> LDS (compiler waits H loads at vmcnt>=2*K/32: W stays in flight) ---
#pragma unroll
    for (int ii = 0; ii < HI; ++ii) {
      int idx = t + ii * 256;
      int r = idx / (K / 8), ch = idx % (K / 8);
      if (F32IN) {
        bf16x8 o;
#pragma unroll
        for (int j = 0; j < 4; ++j) { o[j] = (__bf16)ha[ii][j]; o[4 + j] = (__bf16)hb4[ii][j]; }
        *(bf16x8*)&Hl[r][ch * 8] = o;
      } else {
        *(bf16x8*)&Hl[r][ch * 8] = hr[ii];
      }
    }
    asm volatile("s_waitcnt lgkmcnt(0)" ::: "memory");   // H in LDS
    if (K == 128) asm volatile("s_waitcnt vmcnt(4)" ::: "memory");  // W1 done
    else          asm volatile("s_waitcnt vmcnt(2)" ::: "memory");
    __builtin_amdgcn_s_barrier();
    asm volatile("" ::: "memory");
    // --- MFMA tile 1 (Wl0) ---
    f32x4 acc1[4] = {}, acc2[4] = {};
#pragma unroll
    for (int kk = 0; kk < K / 32; ++kk) {
      bf16x8 af = *(const bf16x8*)&Hl[wave * 16 + l15][kk * 32 + q * 8];
#pragma unroll
      for (int c = 0; c < 4; ++c) {
        bf16x8 bfr = *(const bf16x8*)&Wl0[((kk * 4 + q) * 64 + c * 16 + l15) * 8];
        acc1[c] = __builtin_amdgcn_mfma_f32_16x16x32_bf16(af, bfr, acc1[c], 0, 0, 0);
      }
    }
    asm volatile("s_waitcnt vmcnt(0)" ::: "memory");     // W2 done (no stores yet)
    __builtin_amdgcn_s_barrier();
    asm volatile("" ::: "memory");
    // --- MFMA tile 2 (Wl1) ---
#pragma unroll
    for (int kk = 0; kk < K / 32; ++kk) {
      bf16x8 af = *(const bf16x8*)&Hl[wave * 16 + l15][kk * 32 + q * 8];
#pragma unroll
      for (int c = 0; c < 4; ++c) {
        bf16x8 bfr = *(const bf16x8*)&Wl1[((kk * 4 + q) * 64 + c * 16 + l15) * 8];
        acc2[c] = __builtin_amdgcn_mfma_f32_16x16x32_bf16(af, bfr, acc2[c], 0, 0, 0);
      }
    }
    // --- epilogues ---
    if (pr == 0) {                      // two self tiles: c0 = 0 and 64
#pragma unroll
      for (int h = 0; h < 2; ++h) {
        f32x4* acc = h ? acc2 : acc1;
        int c0 = h * 64;
#pragma unroll
        for (int c = 0; c < 4; ++c) {
          float bc = bias_self[c0 + c * 16 + l15];
#pragma unroll
          for (int i = 0; i < 4; ++i) {
            int g = g0 + wave * 16 + q * 4 + i;
            if (F32OUT)
              outF[(long)g * HIDD + c0 + c * 16 + l15] = acc[c][i] + bc;
            else
              outB[(long)g * HIDD + c0 + c * 16 + l15] = (__bf16)(acc[c][i] + bc);
          }
        }
      }
    } else {                            // two edge tiles: same e, o0 = 0 and 64
      int e = pr - 1;
      float iv[4];
#pragma unroll
      for (int i = 0; i < 4; ++i) {
        int gg = g0 + wave * 16 + q * 4 + i;
        float d = degp[gg] + degp[16384 + gg] + degp[32768 + gg] + degp[49152 + gg];
        iv[i] = d > 0.f ? 1.f / d : 0.f;       // bit-identical to k_inv
      }
      int b4e  = (g0 >> 9) * 4 + e;
      int octg = ((g0 & 511) >> 3) + wave * 2 + (q >> 1);
      int j0   = (q & 1) * 4;
#pragma unroll
      for (int h = 0; h < 2; ++h) {
        f32x4* acc = h ? acc2 : acc1;
        int o0 = h * 64;
#pragma unroll
        for (int c = 0; c < 4; ++c) {
          int o = o0 + c * 16 + l15;
          float bc = bias_edge[o * 4 + e];
          bf16x4 v4;
#pragma unroll
          for (int i = 0; i < 4; ++i) v4[i] = (__bf16)((acc[c][i] + bc) * iv[i]);
          *(bf16x4*)(mmp + ((long)(b4e * 64 + octg) * HIDD + o) * 8 + j0) = v4;
        }
      }
    }
  }
}

// ---------------- phase: spmm (r13-proven: 4-deep ring pipeline) ----------------
__device__ void spmm_phase(char* smem, const uint32_t* __restrict__ bm,
                           const __bf16* __restrict__ mmp,
                           __bf16* __restrict__ part, int bid, int t) {
  int wave = t >> 6, lane = t & 63, l15 = lane & 15, q = lane >> 4;
  int tile = bid >> 7;                  // 0..7 = nt*2 + oc
  int eb   = bid & 127;                 // e*32 + b
  int e = eb >> 5, b = eb & 31;
  int nt = tile >> 1, oc = tile & 1;
  int n0 = nt * 128, o0 = oc * 64;

  const uint32_t* bmr = bm + ((long)((b * 4 + e) * 512 + n0 + wave * 32 + l15)) * 16;
  uint32_t rm0[16], rm1[16];
#pragma unroll
  for (int i = 0; i < 4; ++i) {
    uint4v v0 = *(const uint4v*)(bmr + i * 4);
    uint4v v1 = *(const uint4v*)(bmr + 256 + i * 4);   // +16 rows * 16 words
    rm0[i * 4 + 0] = v0.x; rm0[i * 4 + 1] = v0.y; rm0[i * 4 + 2] = v0.z; rm0[i * 4 + 3] = v0.w;
    rm1[i * 4 + 0] = v1.x; rm1[i * 4 + 1] = v1.y; rm1[i * 4 + 2] = v1.z; rm1[i * 4 + 3] = v1.w;
  }

  // per-wave stage of phase mc: 2 octets (1 KB each, lane*16 linear dest)
  auto stage = [&](int mc, char* dst) {
#pragma unroll
    for (int i = 0; i < 2; ++i) {
      int oct = wave * 2 + i;
      const char* g = (const char*)mmp +
          ((long)(b * 4 + e) * 65536 + mc * 8192 + oct * 1024 + o0 * 8) * 2;
      __builtin_amdgcn_global_load_lds(GLB(g + lane * 16),
                                       LDSp(dst + oct * 1024), 16, 0, 0);
    }
  };

  stage(0, smem);                      // prologue: 3 phases in flight
  stage(1, smem + 8192);
  stage(2, smem + 16384);

  f32x4 acc0[4] = {}, acc1[4] = {};
#pragma unroll
  for (int mc = 0; mc < 8; ++mc) {
    // wait for phase mc's 2 loads (oldest); leave later phases in flight
    if (mc <= 5)      asm volatile("s_waitcnt vmcnt(4)" ::: "memory");
    else if (mc == 6) asm volatile("s_waitcnt vmcnt(2)" ::: "memory");
    else              asm volatile("s_waitcnt vmcnt(0)" ::: "memory");
    __builtin_amdgcn_s_barrier();
    asm volatile("" ::: "memory");
    if (mc < 5) stage(mc + 3, smem + ((mc + 3) & 3) * 8192);
    const __bf16* Bl = (const __bf16*)(smem + (mc & 3) * 8192);
#pragma unroll
    for (int kk = 0; kk < 2; ++kk) {
      uint32_t bits0 = (rm0[mc * 2 + kk] >> (q * 8)) & 0xffu;
      uint32_t bits1 = (rm1[mc * 2 + kk] >> (q * 8)) & 0xffu;
      ushort8v a0, a1;
#pragma unroll
      for (int j = 0; j < 8; ++j) {
        a0[j] = (bits0 >> j & 1u) ? (unsigned short)0x3F80 : (unsigned short)0;
        a1[j] = (bits1 >> j & 1u) ? (unsigned short)0x3F80 : (unsigned short)0;
      }
      union { ushort8v u; bf16x8 v; } c0, c1; c0.u = a0; c1.u = a1;
#pragma unroll
      for (int c = 0; c < 4; ++c) {
        bf16x8 bfr = *(const bf16x8*)&Bl[((kk * 4 + q) * 64 + c * 16 + l15) * 8];
        acc0[c] = __builtin_amdgcn_mfma_f32_16x16x32_bf16(c0.v, bfr, acc0[c], 0, 0, 0);
        acc1[c] = __builtin_amdgcn_mfma_f32_16x16x32_bf16(c1.v, bfr, acc1[c], 0, 0, 0);
      }
    }
  }

  __bf16* dst = part + (long)(e * 32 + b) * NNODE * HIDD;
#pragma unroll
  for (int c = 0; c < 4; ++c) {
#pragma unroll
    for (int i = 0; i < 4; ++i) {
      int n = n0 + wave * 32 + q * 4 + i;
      int o = o0 + c * 16 + l15;
      dst[(long)n * HIDD + o] = (__bf16)acc0[c][i];
      dst[(long)(n + 16) * HIDD + o] = (__bf16)acc1[c][i];
    }
  }
}

// ---------------- phase: bnstat (r20: one wave per n, barrier-free) ----------------
// 512 blocks x 64 threads. Lane holds 16 bf16x4 chunks in registers (b =
// (lane>>5) + i*2, o-chunk = lane&31), sums locally, shfl_xor tree reduce
// (all lanes get totals), computes sc/sh redundantly, normalizes from
// registers. Zero barriers, zero LDS.
template <bool HASP>
__global__ __launch_bounds__(64) void g_bnstat(const __bf16* __restrict__ hs,
                                               const __bf16* __restrict__ part,
                                               const float* __restrict__ gg,
                                               const float* __restrict__ bb,
                                               __bf16* __restrict__ hb) {
  int n = blockIdx.x;                  // one n per wave
  int lane = threadIdx.x;
  int o4 = lane & 31;                  // o-chunk index (4 elems)
  int bq = lane >> 5;                  // 0/1
  f32x4 v[16];
  float s = 0.f, sq = 0.f;
#pragma unroll
  for (int i = 0; i < 16; ++i) {
    int b = bq + i * 2;
    long base = ((long)b * NNODE + n) * HIDD + o4 * 4;
    bf16x4 hv = *(const bf16x4*)(hs + base);
    f32x4 t;
#pragma unroll
    for (int j = 0; j < 4; ++j) t[j] = (float)hv[j];
    if (HASP) {
#pragma unroll
      for (int e = 0; e < 4; ++e) {
        bf16x4 pv = *(const bf16x4*)(part + ((long)(e * 32 + b) * NNODE + n) * HIDD + o4 * 4);
#pragma unroll
        for (int j = 0; j < 4; ++j) t[j] += (float)pv[j];
      }
    }
    v[i] = t;
#pragma unroll
    for (int j = 0; j < 4; ++j) { s += t[j]; sq += t[j] * t[j]; }
  }
#pragma unroll
  for (int off = 1; off < 64; off <<= 1) {
    s  += __shfl_xor(s, off);
    sq += __shfl_xor(sq, off);
  }
  float mean = s * (1.f / 4096.f);
  float var = sq * (1.f / 4096.f) - mean * mean;   // biased, torch BN1d
  float rstd = rsqrtf(var + 1e-5f);
  float sc = gg[n] * rstd;
  float sh = bb[n] - mean * sc;
#pragma unroll
  for (int i = 0; i < 16; ++i) {
    int b = bq + i * 2;
    bf16x4 o;
#pragma unroll
    for (int j = 0; j < 4; ++j) {
      float x = v[i][j] * sc + sh;
      o[j] = (__bf16)(x > 0.f ? x : 0.f);
    }
    *(bf16x4*)(hb + ((long)b * NNODE + n) * HIDD + o4 * 4) = o;
  }
}

// ---------------- kernels ----------------
__global__ __launch_bounds__(256) void g_packprep(Params P) {
  pack_phase(P.adj, P.bm, P.degp, blockIdx.x, threadIdx.x, gridDim.x);
  prep_phase(P, blockIdx.x, threadIdx.x, gridDim.x);
}
template <int K, bool F32IN, bool F32OUT>
__global__ __launch_bounds__(256) void g_gemm(const void* hv, const __bf16* wps,
                                              const float* bs, const __bf16* wpe,
                                              const float* be, const float* degp,
                                              float* outF, __bf16* outB,
                                              __bf16* mmp, int npairs) {
  __shared__ __align__(16) char smem[64 * (K + 8) * 2 + 2 * K * 64 * 2];
  gemm_phase<K, F32IN, F32OUT>(smem, hv, wps, bs, wpe, be, degp, outF, outB,
                               mmp, npairs, blockIdx.x, threadIdx.x, gridDim.x);
}
__global__ __launch_bounds__(256) void g_spmm(const uint32_t* bm, const __bf16* mmp,
                                              __bf16* part) {
  __shared__ __align__(16) char smem[32768];
  spmm_phase(smem, bm, mmp, part, blockIdx.x, threadIdx.x);
}

extern "C" void kernel_launch(void* const* d_in, const int* in_sizes, int n_in,
                              void* d_out, int out_size, void* d_ws, size_t ws_size,
                              hipStream_t stream) {
  (void)in_sizes; (void)n_in; (void)out_size; (void)ws_size;
  Params P;
  P.x   = (const float*)d_in[0];
  P.adj = (const float*)d_in[1];
  for (int l = 0; l < 3; ++l) {
    P.wself[l] = (const float*)d_in[2 + 6 * l];
    P.bself[l] = (const float*)d_in[3 + 6 * l];
    P.wedge[l] = (const float*)d_in[4 + 6 * l];
    P.bedge[l] = (const float*)d_in[5 + 6 * l];
    P.bng[l]   = (const float*)d_in[6 + 6 * l];
    P.bnb[l]   = (const float*)d_in[7 + 6 * l];
  }
  P.w1   = (const float*)d_in[20];
  P.b1   = (const float*)d_in[21];
  P.bnfg = (const float*)d_in[22];
  P.bnfb = (const float*)d_in[23];
  P.w2   = (const float*)d_in[24];
  P.b2   = (const float*)d_in[25];

  char* ws = (char*)d_ws;
  P.mmp  = (__bf16*)ws;                  // 16,777,216
  P.hs   = (__bf16*)(ws + 16777216);     //  4,194,304 used (slot 8 MB, bf16)
  P.part = (__bf16*)(ws + 25165824);     // 16,777,216 (bf16)
  P.hb0  = (__bf16*)(ws + 41943040);     //  4,194,304
  P.hb1  = (__bf16*)(ws + 46137344);     //  4,194,304
  P.bm   = (uint32_t*)(ws + 50331648);   //  4,194,304
  P.degp = (float*)(ws + 54525952);      //    262,144
  P.wp   = (__bf16*)(ws + 54788096);     //    475,136 -> ~55.3 MB total
  P.out  = (float*)d_out;

  g_packprep<<<16384, 256, 0, stream>>>(P);

  // layer 0 (K=64, fp32 input x): 1280 by-pairs
  g_gemm<64, true, false><<<1280, 256, 0, stream>>>(P.x, P.wp + WP_S0, P.bself[0],
      P.wp + WP_E0, P.bedge[0], P.degp, nullptr, P.hs, P.mmp, 1280);
  g_spmm<<<1024, 256, 0, stream>>>(P.bm, P.mmp, P.part);
  g_bnstat<true><<<512, 64, 0, stream>>>(P.hs, P.part, P.bng[0], P.bnb[0], P.hb0);

  // layer 1 (K=128)
  g_gemm<128, false, false><<<1280, 256, 0, stream>>>(P.hb0, P.wp + WP_S1, P.bself[1],
      P.wp + WP_E1, P.bedge[1], P.degp, nullptr, P.hs, P.mmp, 1280);
  g_spmm<<<1024, 256, 0, stream>>>(P.bm, P.mmp, P.part);
  g_bnstat<true><<<512, 64, 0, stream>>>(P.hs, P.part, P.bng[1], P.bnb[1], P.hb1);

  // layer 2 (K=128)
  g_gemm<128, false, false><<<1280, 256, 0, stream>>>(P.hb1, P.wp + WP_S2, P.bself[2],
      P.wp + WP_E2, P.bedge[2], P.degp, nullptr, P.hs, P.mmp, 1280);
  g_spmm<<<1024, 256, 0, stream>>>(P.bm, P.mmp, P.part);
  g_bnstat<true><<<512, 64, 0, stream>>>(P.hs, P.part, P.bng[2], P.bnb[2], P.hb0);

  // head: w1 -> BN -> relu -> w2 (pairs: 256 each, self-only)
  g_gemm<128, false, false><<<256, 256, 0, stream>>>(P.hb0, P.wp + WP_W1, P.b1,
      nullptr, nullptr, P.degp, nullptr, P.hs, nullptr, 256);
  g_bnstat<false><<<512, 64, 0, stream>>>(P.hs, nullptr, P.bnfg, P.bnfb, P.hb1);
  g_gemm<128, false, true><<<256, 256, 0, stream>>>(P.hb1, P.wp + WP_W2, P.b2,
      nullptr, nullptr, P.degp, P.out, nullptr, nullptr, 256);
}

// Round 12
// 341.879 us; speedup vs baseline: 1.3155x; 1.0135x over previous
//
#include <hip/hip_runtime.h>
#include <stdint.h>

// RGCN round 21. Base = r20 champion (346.5us). ONE change: spmm oc-merge.
// Old: 1024 blocks (e,b,nt,oc), 8KB o-half stages, bm masks loaded TWICE
// (once per oc), 1024 block prologues. New: 512 blocks (e,b,nt), full 16KB
// chunk stages (4 gload_lds/wave/phase), both o-halves computed (acc[8],
// 32 MFMA/wave/phase), same 8 phases + 4-deep ring. vmcnt: 4 loads/stage,
// 3 in flight -> vmcnt(8)/(4)/(0). LDS 64KB -> 2 blocks/CU (grid 512
// exactly resident). Per-output FMA order unchanged -> bit-identical,
// absmax 0.03125. Halves bm reads + prologues + dispatch tail.
// Everything else byte-identical to r20.

typedef float  f32x4  __attribute__((ext_vector_type(4)));
typedef __bf16 bf16x8 __attribute__((ext_vector_type(8)));
typedef __bf16 bf16x4 __attribute__((ext_vector_type(4)));
typedef unsigned short ushort8v __attribute__((ext_vector_type(8)));
typedef uint32_t uint4v __attribute__((ext_vector_type(4)));

#define MBATCH 32
#define ETYPES 4
#define NNODE  512
#define HIDD   128

#define GLB(p) (const __attribute__((address_space(1))) uint32_t*)(p)
#define LDSp(p) (__attribute__((address_space(3))) uint32_t*)(p)

// packed-weight pool offsets (elements)
#define WP_S0 0
#define WP_E0 8192
#define WP_S1 40960
#define WP_E1 57344
#define WP_S2 122880
#define WP_E2 139264
#define WP_W1 204800
#define WP_W2 221184

struct Params {
  const float* x;
  const float* adj;
  const float* wself[3]; const float* bself[3];
  const float* wedge[3]; const float* bedge[3];
  const float* bng[3];   const float* bnb[3];
  const float* w1; const float* b1;
  const float* bnfg; const float* bnfb;
  const float* w2; const float* b2;
  __bf16* mmp; __bf16* hs; __bf16* part;
  __bf16* hb0; __bf16* hb1;
  uint32_t* bm; float* degp; __bf16* wp;
  float* out;
};

// ---------------- phase: pack (r9-proven ballot body) ----------------
__device__ void pack_phase(const float* __restrict__ adj, uint32_t* __restrict__ bm,
                           float* __restrict__ degp, int bid, int t, int nbl) {
  int wave = t >> 6, lane = t & 63;
  for (int rg = bid; rg < 16384; rg += nbl) {
    int r = rg * 4 + wave;                  // 65536 rows (b,e,n)
    int b = r >> 11, e = (r >> 9) & 3, n = r & 511;
    const float* row = adj + (long)r * 512;
    uint32_t myw = 0;
#pragma unroll
    for (int i = 0; i < 8; ++i) {
      uint64_t bal = __ballot(row[i * 64 + lane] != 0.f);
      uint32_t lo = (uint32_t)bal, hi = (uint32_t)(bal >> 32);
      if ((lane >> 1) == i) myw = (lane & 1) ? hi : lo;
    }
    if (lane == (n >> 5)) myw &= ~(1u << (n & 31));   // zero diagonal
    int pc = (lane < 16) ? __popc(myw) : 0;
    pc += __shfl_down(pc, 8);
    pc += __shfl_down(pc, 4);
    pc += __shfl_down(pc, 2);
    pc += __shfl_down(pc, 1);
    if (lane < 16) bm[(long)r * 16 + lane] = myw;
    if (lane == 0) degp[e * 16384 + b * 512 + n] = (float)pc;
  }
}

// ---------------- phase: prep (r9-proven body) ----------------
__device__ void prep_phase(const Params& P, int bid, int t, int nbl) {
  const float* Ws[8] = {P.wself[0], P.wedge[0], P.wself[1], P.wedge[1],
                        P.wself[2], P.wedge[2], P.w1, P.w2};
  const int Kt[8]  = {64, 64, 128, 128, 128, 128, 128, 128};
  const int NB[8]  = {2, 8, 2, 8, 2, 8, 2, 2};
  const int OFF[8] = {WP_S0, WP_E0, WP_S1, WP_E1, WP_S2, WP_E2, WP_W1, WP_W2};
#pragma unroll
  for (int wid = 0; wid < 8; ++wid) {
    int K = Kt[wid], nblk = NB[wid];
    int tot = K * nblk * 64;
    for (int gid = bid * 256 + t; gid < tot; gid += nbl * 256) {
      int c = gid & 63;
      int k = (gid >> 6) % K;
      int blk = (gid >> 6) / K;
      int edge = (nblk == 8);
      int WS = edge ? 512 : 128;
      int col = edge ? (((blk & 1) * 64 + c) * 4 + (blk >> 1)) : (blk * 64 + c);
      P.wp[OFF[wid] + (long)blk * K * 64 + (k >> 3) * 512 + c * 8 + (k & 7)] =
          (__bf16)Ws[wid][k * WS + col];
    }
  }
}

// ---------------- phase: gemm (r19: by-pair per block, W dbuf, counted vmcnt) ----
// pair pr covers by1=2pr, by2=2pr+1 for one g0. pr==0: both self (c0 0/64);
// pr>=1: both edge, same e=pr-1, o0 0/64. H staged once per pair.
template <int K, bool F32IN, bool F32OUT>
__device__ void gemm_phase(char* smem, const void* __restrict__ hv,
                           const __bf16* __restrict__ wp_self,
                           const float* __restrict__ bias_self,
                           const __bf16* __restrict__ wp_edge,
                           const float* __restrict__ bias_edge,
                           const float* __restrict__ degp,
                           float* __restrict__ outF, __bf16* __restrict__ outB,
                           __bf16* __restrict__ mmp,
                           int npairs, int bid, int t, int nbl) {
  __bf16 (*Hl)[K + 8] = (__bf16(*)[K + 8])smem;
  __bf16* Wl0 = (__bf16*)(smem + 64 * (K + 8) * 2);   // k-packed [K/8][64][8]
  __bf16* Wl1 = Wl0 + K * 64;
  constexpr int HI = K / 32;           // H chunks per thread
  int wave = t >> 6, lane = t & 63, l15 = lane & 15, q = lane >> 4;
  for (int pairi = bid; pairi < npairs; pairi += nbl) {
    __syncthreads();                   // smem free from prev pair
    int g0 = (pairi & 255) * 64;
    int pr = pairi >> 8;
    // --- H loads first (vmcnt retires in issue order: keeps W countable) ---
    f32x4 ha[F32IN ? HI : 1], hb4[F32IN ? HI : 1];
    bf16x8 hr[F32IN ? 1 : HI];
#pragma unroll
    for (int ii = 0; ii < HI; ++ii) {
      int idx = t + ii * 256;
      int r = idx / (K / 8), ch = idx % (K / 8);
      if (F32IN) {
        const float* xf = (const float*)hv;
        ha[ii]  = *(const f32x4*)(xf + (long)(g0 + r) * K + ch * 8);
        hb4[ii] = *(const f32x4*)(xf + (long)(g0 + r) * K + ch * 8 + 4);
      } else {
        const __bf16* hbp = (const __bf16*)hv;
        hr[ii] = *(const bf16x8*)(hbp + (long)(g0 + r) * K + ch * 8);
      }
    }
    __builtin_amdgcn_sched_barrier(0);
    // --- issue W1 then W2 (K/32 gload_lds each per wave) ---
    {
      const __bf16* wb1 = (pr >= 1) ? (wp_edge + (long)(pr * 2 - 2) * K * 64)
                                    : wp_self;
      const __bf16* wb2 = (pr >= 1) ? (wp_edge + (long)(pr * 2 - 1) * K * 64)
                                    : (wp_self + (long)K * 64);
      const char* g1 = (const char*)wb1;
      const char* g2 = (const char*)wb2;
#pragma unroll
      for (int i = 0; i < K / 32; ++i)
        __builtin_amdgcn_global_load_lds(GLB(g1 + i * 4096 + wave * 1024 + lane * 16),
                                         LDSp((char*)Wl0 + i * 4096 + wave * 1024),
                                         16, 0, 0);
#pragma unroll
      for (int i = 0; i < K / 32; ++i)
        __builtin_amdgcn_global_load_lds(GLB(g2 + i * 4096 + wave * 1024 + lane * 16),
                                         LDSp((char*)Wl1 + i * 4096 + wave * 1024),
                                         16, 0, 0);
    }
    __builtin_amdgcn_sched_barrier(0);
    // --- H -> LDS (compiler waits H loads at vmcnt>=2*K/32: W stays in flight) ---
#pragma unroll
    for (int ii = 0; ii < HI; ++ii) {
      int idx = t + ii * 256;
      int r = idx / (K / 8), ch = idx % (K / 8);
      if (F32IN) {
        bf16x8 o;
#pragma unroll
        for (int j = 0; j < 4; ++j) { o[j] = (__bf16)ha[ii][j]; o[4 + j] = (__bf16)hb4[ii][j]; }
        *(bf16x8*)&Hl[r][ch * 8] = o;
      } else {
        *(bf16x8*)&Hl[r][ch * 8] = hr[ii];
      }
    }
    asm volatile("s_waitcnt lgkmcnt(0)" ::: "memory");   // H in LDS
    if (K == 128) asm volatile("s_waitcnt vmcnt(4)" ::: "memory");  // W1 done
    else          asm volatile("s_waitcnt vmcnt(2)" ::: "memory");
    __builtin_amdgcn_s_barrier();
    asm volatile("" ::: "memory");
    // --- MFMA tile 1 (Wl0) ---
    f32x4 acc1[4] = {}, acc2[4] = {};
#pragma unroll
    for (int kk = 0; kk < K / 32; ++kk) {
      bf16x8 af = *(const bf16x8*)&Hl[wave * 16 + l15][kk * 32 + q * 8];
#pragma unroll
      for (int c = 0; c < 4; ++c) {
        bf16x8 bfr = *(const bf16x8*)&Wl0[((kk * 4 + q) * 64 + c * 16 + l15) * 8];
        acc1[c] = __builtin_amdgcn_mfma_f32_16x16x32_bf16(af, bfr, acc1[c], 0, 0, 0);
      }
    }
    asm volatile("s_waitcnt vmcnt(0)" ::: "memory");     // W2 done (no stores yet)
    __builtin_amdgcn_s_barrier();
    asm volatile("" ::: "memory");
    // --- MFMA tile 2 (Wl1) ---
#pragma unroll
    for (int kk = 0; kk < K / 32; ++kk) {
      bf16x8 af = *(const bf16x8*)&Hl[wave * 16 + l15][kk * 32 + q * 8];
#pragma unroll
      for (int c = 0; c < 4; ++c) {
        bf16x8 bfr = *(const bf16x8*)&Wl1[((kk * 4 + q) * 64 + c * 16 + l15) * 8];
        acc2[c] = __builtin_amdgcn_mfma_f32_16x16x32_bf16(af, bfr, acc2[c], 0, 0, 0);
      }
    }
    // --- epilogues ---
    if (pr == 0) {                      // two self tiles: c0 = 0 and 64
#pragma unroll
      for (int h = 0; h < 2; ++h) {
        f32x4* acc = h ? acc2 : acc1;
        int c0 = h * 64;
#pragma unroll
        for (int c = 0; c < 4; ++c) {
          float bc = bias_self[c0 + c * 16 + l15];
#pragma unroll
          for (int i = 0; i < 4; ++i) {
            int g = g0 + wave * 16 + q * 4 + i;
            if (F32OUT)
              outF[(long)g * HIDD + c0 + c * 16 + l15] = acc[c][i] + bc;
            else
              outB[(long)g * HIDD + c0 + c * 16 + l15] = (__bf16)(acc[c][i] + bc);
          }
        }
      }
    } else {                            // two edge tiles: same e, o0 = 0 and 64
      int e = pr - 1;
      float iv[4];
#pragma unroll
      for (int i = 0; i < 4; ++i) {
        int gg = g0 + wave * 16 + q * 4 + i;
        float d = degp[gg] + degp[16384 + gg] + degp[32768 + gg] + degp[49152 + gg];
        iv[i] = d > 0.f ? 1.f / d : 0.f;       // bit-identical to k_inv
      }
      int b4e  = (g0 >> 9) * 4 + e;
      int octg = ((g0 & 511) >> 3) + wave * 2 + (q >> 1);
      int j0   = (q & 1) * 4;
#pragma unroll
      for (int h = 0; h < 2; ++h) {
        f32x4* acc = h ? acc2 : acc1;
        int o0 = h * 64;
#pragma unroll
        for (int c = 0; c < 4; ++c) {
          int o = o0 + c * 16 + l15;
          float bc = bias_edge[o * 4 + e];
          bf16x4 v4;
#pragma unroll
          for (int i = 0; i < 4; ++i) v4[i] = (__bf16)((acc[c][i] + bc) * iv[i]);
          *(bf16x4*)(mmp + ((long)(b4e * 64 + octg) * HIDD + o) * 8 + j0) = v4;
        }
      }
    }
  }
}

// ---------------- phase: spmm (r21: oc-merged, full-width chunks) ----------------
// grid = 512 exactly: bid -> (nt 0..3, eb = e*32+b). 8 phases (mc 0..7),
// ring of 4 x 16KB LDS buffers, 4 gload_lds per wave per phase (full 128-col
// chunk). vmcnt: 4 loads/stage, 3 stages in flight -> wait vmcnt(8) for
// mc<=5, (4) at 6, (0) at 7. Both o-halves computed: acc[8], 32 MFMA/wave/
// phase. bm masks loaded once per (e,b,nt). Per-output FMA order identical
// to r20 -> bit-identical results.
__device__ void spmm_phase(char* smem, const uint32_t* __restrict__ bm,
                           const __bf16* __restrict__ mmp,
                           __bf16* __restrict__ part, int bid, int t) {
  int wave = t >> 6, lane = t & 63, l15 = lane & 15, q = lane >> 4;
  int nt = bid >> 7;                    // 0..3
  int eb = bid & 127;                   // e*32 + b
  int e = eb >> 5, b = eb & 31;
  int n0 = nt * 128;

  const uint32_t* bmr = bm + ((long)((b * 4 + e) * 512 + n0 + wave * 32 + l15)) * 16;
  uint32_t rm0[16], rm1[16];
#pragma unroll
  for (int i = 0; i < 4; ++i) {
    uint4v v0 = *(const uint4v*)(bmr + i * 4);
    uint4v v1 = *(const uint4v*)(bmr + 256 + i * 4);   // +16 rows * 16 words
    rm0[i * 4 + 0] = v0.x; rm0[i * 4 + 1] = v0.y; rm0[i * 4 + 2] = v0.z; rm0[i * 4 + 3] = v0.w;
    rm1[i * 4 + 0] = v1.x; rm1[i * 4 + 1] = v1.y; rm1[i * 4 + 2] = v1.z; rm1[i * 4 + 3] = v1.w;
  }

  // per-wave stage of phase mc: 2 octets x 2 halves (1 KB each), linear dest
  auto stage = [&](int mc, char* dst) {
#pragma unroll
    for (int i = 0; i < 2; ++i) {
      int oct = wave * 2 + i;
#pragma unroll
      for (int hf = 0; hf < 2; ++hf) {
        const char* g = (const char*)mmp +
            ((long)(b * 4 + e) * 65536 + mc * 8192 + oct * 1024 + hf * 512) * 2;
        __builtin_amdgcn_global_load_lds(GLB(g + lane * 16),
                                         LDSp(dst + oct * 2048 + hf * 1024), 16, 0, 0);
      }
    }
  };

  stage(0, smem);                      // prologue: 3 phases in flight (12 loads)
  stage(1, smem + 16384);
  stage(2, smem + 32768);

  f32x4 acc0[8] = {}, acc1[8] = {};
#pragma unroll
  for (int mc = 0; mc < 8; ++mc) {
    // wait for phase mc's 4 loads (oldest); leave later phases in flight
    if (mc <= 5)      asm volatile("s_waitcnt vmcnt(8)" ::: "memory");
    else if (mc == 6) asm volatile("s_waitcnt vmcnt(4)" ::: "memory");
    else              asm volatile("s_waitcnt vmcnt(0)" ::: "memory");
    __builtin_amdgcn_s_barrier();
    asm volatile("" ::: "memory");
    if (mc < 5) stage(mc + 3, smem + ((mc + 3) & 3) * 16384);
    const __bf16* Bl = (const __bf16*)(smem + (mc & 3) * 16384);
#pragma unroll
    for (int kk = 0; kk < 2; ++kk) {
      uint32_t bits0 = (rm0[mc * 2 + kk] >> (q * 8)) & 0xffu;
      uint32_t bits1 = (rm1[mc * 2 + kk] >> (q * 8)) & 0xffu;
      ushort8v a0, a1;
#pragma unroll
      for (int j = 0; j < 8; ++j) {
        a0[j] = (bits0 >> j & 1u) ? (unsigned short)0x3F80 : (unsigned short)0;
        a1[j] = (bits1 >> j & 1u) ? (unsigned short)0x3F80 : (unsigned short)0;
      }
      union { ushort8v u; bf16x8 v; } c0, c1; c0.u = a0; c1.u = a1;
#pragma unroll
      for (int c = 0; c < 8; ++c) {
        bf16x8 bfr = *(const bf16x8*)&Bl[((kk * 4 + q) * 128 + c * 16 + l15) * 8];
        acc0[c] = __builtin_amdgcn_mfma_f32_16x16x32_bf16(c0.v, bfr, acc0[c], 0, 0, 0);
        acc1[c] = __builtin_amdgcn_mfma_f32_16x16x32_bf16(c1.v, bfr, acc1[c], 0, 0, 0);
      }
    }
  }

  __bf16* dst = part + (long)(e * 32 + b) * NNODE * HIDD;
#pragma unroll
  for (int c = 0; c < 8; ++c) {
#pragma unroll
    for (int i = 0; i < 4; ++i) {
      int n = n0 + wave * 32 + q * 4 + i;
      int o = c * 16 + l15;
      dst[(long)n * HIDD + o] = (__bf16)acc0[c][i];
      dst[(long)(n + 16) * HIDD + o] = (__bf16)acc1[c][i];
    }
  }
}

// ---------------- phase: bnstat (r20: one wave per n, barrier-free) ----------------
template <bool HASP>
__global__ __launch_bounds__(64) void g_bnstat(const __bf16* __restrict__ hs,
                                               const __bf16* __restrict__ part,
                                               const float* __restrict__ gg,
                                               const float* __restrict__ bb,
                                               __bf16* __restrict__ hb) {
  int n = blockIdx.x;                  // one n per wave
  int lane = threadIdx.x;
  int o4 = lane & 31;                  // o-chunk index (4 elems)
  int bq = lane >> 5;                  // 0/1
  f32x4 v[16];
  float s = 0.f, sq = 0.f;
#pragma unroll
  for (int i = 0; i < 16; ++i) {
    int b = bq + i * 2;
    long base = ((long)b * NNODE + n) * HIDD + o4 * 4;
    bf16x4 hv = *(const bf16x4*)(hs + base);
    f32x4 t;
#pragma unroll
    for (int j = 0; j < 4; ++j) t[j] = (float)hv[j];
    if (HASP) {
#pragma unroll
      for (int e = 0; e < 4; ++e) {
        bf16x4 pv = *(const bf16x4*)(part + ((long)(e * 32 + b) * NNODE + n) * HIDD + o4 * 4);
#pragma unroll
        for (int j = 0; j < 4; ++j) t[j] += (float)pv[j];
      }
    }
    v[i] = t;
#pragma unroll
    for (int j = 0; j < 4; ++j) { s += t[j]; sq += t[j] * t[j]; }
  }
#pragma unroll
  for (int off = 1; off < 64; off <<= 1) {
    s  += __shfl_xor(s, off);
    sq += __shfl_xor(sq, off);
  }
  float mean = s * (1.f / 4096.f);
  float var = sq * (1.f / 4096.f) - mean * mean;   // biased, torch BN1d
  float rstd = rsqrtf(var + 1e-5f);
  float sc = gg[n] * rstd;
  float sh = bb[n] - mean * sc;
#pragma unroll
  for (int i = 0; i < 16; ++i) {
    int b = bq + i * 2;
    bf16x4 o;
#pragma unroll
    for (int j = 0; j < 4; ++j) {
      float x = v[i][j] * sc + sh;
      o[j] = (__bf16)(x > 0.f ? x : 0.f);
    }
    *(bf16x4*)(hb + ((long)b * NNODE + n) * HIDD + o4 * 4) = o;
  }
}

// ---------------- kernels ----------------
__global__ __launch_bounds__(256) void g_packprep(Params P) {
  pack_phase(P.adj, P.bm, P.degp, blockIdx.x, threadIdx.x, gridDim.x);
  prep_phase(P, blockIdx.x, threadIdx.x, gridDim.x);
}
template <int K, bool F32IN, bool F32OUT>
__global__ __launch_bounds__(256) void g_gemm(const void* hv, const __bf16* wps,
                                              const float* bs, const __bf16* wpe,
                                              const float* be, const float* degp,
                                              float* outF, __bf16* outB,
                                              __bf16* mmp, int npairs) {
  __shared__ __align__(16) char smem[64 * (K + 8) * 2 + 2 * K * 64 * 2];
  gemm_phase<K, F32IN, F32OUT>(smem, hv, wps, bs, wpe, be, degp, outF, outB,
                               mmp, npairs, blockIdx.x, threadIdx.x, gridDim.x);
}
__global__ __launch_bounds__(256) void g_spmm(const uint32_t* bm, const __bf16* mmp,
                                              __bf16* part) {
  __shared__ __align__(16) char smem[65536];
  spmm_phase(smem, bm, mmp, part, blockIdx.x, threadIdx.x);
}

extern "C" void kernel_launch(void* const* d_in, const int* in_sizes, int n_in,
                              void* d_out, int out_size, void* d_ws, size_t ws_size,
                              hipStream_t stream) {
  (void)in_sizes; (void)n_in; (void)out_size; (void)ws_size;
  Params P;
  P.x   = (const float*)d_in[0];
  P.adj = (const float*)d_in[1];
  for (int l = 0; l < 3; ++l) {
    P.wself[l] = (const float*)d_in[2 + 6 * l];
    P.bself[l] = (const float*)d_in[3 + 6 * l];
    P.wedge[l] = (const float*)d_in[4 + 6 * l];
    P.bedge[l] = (const float*)d_in[5 + 6 * l];
    P.bng[l]   = (const float*)d_in[6 + 6 * l];
    P.bnb[l]   = (const float*)d_in[7 + 6 * l];
  }
  P.w1   = (const float*)d_in[20];
  P.b1   = (const float*)d_in[21];
  P.bnfg = (const float*)d_in[22];
  P.bnfb = (const float*)d_in[23];
  P.w2   = (const float*)d_in[24];
  P.b2   = (const float*)d_in[25];

  char* ws = (char*)d_ws;
  P.mmp  = (__bf16*)ws;                  // 16,777,216
  P.hs   = (__bf16*)(ws + 16777216);     //  4,194,304 used (slot 8 MB, bf16)
  P.part = (__bf16*)(ws + 25165824);     // 16,777,216 (bf16)
  P.hb0  = (__bf16*)(ws + 41943040);     //  4,194,304
  P.hb1  = (__bf16*)(ws + 46137344);     //  4,194,304
  P.bm   = (uint32_t*)(ws + 50331648);   //  4,194,304
  P.degp = (float*)(ws + 54525952);      //    262,144
  P.wp   = (__bf16*)(ws + 54788096);     //    475,136 -> ~55.3 MB total
  P.out  = (float*)d_out;

  g_packprep<<<16384, 256, 0, stream>>>(P);

  // layer 0 (K=64, fp32 input x): 1280 by-pairs
  g_gemm<64, true, false><<<1280, 256, 0, stream>>>(P.x, P.wp + WP_S0, P.bself[0],
      P.wp + WP_E0, P.bedge[0], P.degp, nullptr, P.hs, P.mmp, 1280);
  g_spmm<<<512, 256, 0, stream>>>(P.bm, P.mmp, P.part);
  g_bnstat<true><<<512, 64, 0, stream>>>(P.hs, P.part, P.bng[0], P.bnb[0], P.hb0);

  // layer 1 (K=128)
  g_gemm<128, false, false><<<1280, 256, 0, stream>>>(P.hb0, P.wp + WP_S1, P.bself[1],
      P.wp + WP_E1, P.bedge[1], P.degp, nullptr, P.hs, P.mmp, 1280);
  g_spmm<<<512, 256, 0, stream>>>(P.bm, P.mmp, P.part);
  g_bnstat<true><<<512, 64, 0, stream>>>(P.hs, P.part, P.bng[1], P.bnb[1], P.hb1);

  // layer 2 (K=128)
  g_gemm<128, false, false><<<1280, 256, 0, stream>>>(P.hb1, P.wp + WP_S2, P.bself[2],
      P.wp + WP_E2, P.bedge[2], P.degp, nullptr, P.hs, P.mmp, 1280);
  g_spmm<<<512, 256, 0, stream>>>(P.bm, P.mmp, P.part);
  g_bnstat<true><<<512, 64, 0, stream>>>(P.hs, P.part, P.bng[2], P.bnb[2], P.hb0);

  // head: w1 -> BN -> relu -> w2 (pairs: 256 each, self-only)
  g_gemm<128, false, false><<<256, 256, 0, stream>>>(P.hb0, P.wp + WP_W1, P.b1,
      nullptr, nullptr, P.degp, nullptr, P.hs, nullptr, 256);
  g_bnstat<false><<<512, 64, 0, stream>>>(P.hs, nullptr, P.bnfg, P.bnfb, P.hb1);
  g_gemm<128, false, true><<<256, 256, 0, stream>>>(P.hb1, P.wp + WP_W2, P.b2,
      nullptr, nullptr, P.degp, P.out, nullptr, nullptr, 256);
}